// Round 4
// baseline (8854.267 us; speedup 1.0000x reference)
//
#include <hip/hip_runtime.h>

#define B_ 256
#define S_ 256
#define D_ 64
#define H_ 1024
#define G4 4096
#define TOUT 32

typedef unsigned short u16;
typedef __attribute__((ext_vector_type(8))) short short8;
typedef __attribute__((ext_vector_type(4))) float float4v;

__device__ __forceinline__ float bf2f(u16 b) {
  return __uint_as_float(((unsigned int)b) << 16);
}
__device__ __forceinline__ u16 f2bf(float f) {
  unsigned int u = __float_as_uint(f);
  unsigned int r = (u + 0x7fffu + ((u >> 16) & 1u)) >> 16;
  return (u16)r;
}
__device__ __forceinline__ unsigned pack2(float a, float b) {
  return (unsigned)f2bf(a) | ((unsigned)f2bf(b) << 16);
}
__device__ __forceinline__ float sigm(float x) {
  return 1.f / (1.f + __expf(-x));
}
__device__ __forceinline__ float tanh_(float x) {
  float xc = fminf(fmaxf(x, -15.f), 15.f);
  float e = __expf(2.f * xc);
  return (e - 1.f) / (e + 1.f);
}

__global__ __launch_bounds__(256) void cvt_kernel(const float* __restrict__ src,
                                                  u16* __restrict__ dst, int n) {
  for (int i = blockIdx.x * blockDim.x + threadIdx.x; i < n;
       i += gridDim.x * blockDim.x)
    dst[i] = f2bf(src[i]);
}

__global__ __launch_bounds__(256) void zero_kernel(uint4* __restrict__ p, int n16) {
  for (int i = blockIdx.x * blockDim.x + threadIdx.x; i < n16;
       i += gridDim.x * blockDim.x)
    p[i] = make_uint4(0u, 0u, 0u, 0u);
}

struct LayerDesc {
  const u16* A0; int lda0;
  const u16* A1; int lda1; int klen0;
  const void* W0; int ldw0;
  const void* W1; int ldw1; int Ktot;
  const float* bias;   // fp32 [4096] original gate-blocked
  const float* wcol;   // fp32 [4096] dec input column, or null
  const float* inp;    // fp32 [B] scalar input, or null
  float* c;
  u16* h;
  int active;
};

// Paired LSTM step: blockIdx.y<4 -> dA (layer0 @ t), >=4 -> dB (layer1 @ t-1).
// gates = [A0|A1] @ [W0|W1]^T + bias (+inp*wcol), fused cell epilogue.
// K-loop: depth-2 register prefetch (slots p/q by chunk parity) + LDS double
// buffer -> ONE barrier per chunk; global loads stay in flight across barriers
// (register staging, no global_load_lds, so no vmcnt(0) drain at s_barrier).
template <bool WF32>
__global__ __launch_bounds__(256) void lstm_step_kernel(LayerDesc dA, LayerDesc dB)
{
  const bool second = (blockIdx.y >= 4);
  const LayerDesc d = second ? dB : dA;
  if (!d.active) return;

  __shared__ u16 As[2][64][72];  // +8 pad: free 2-way bank conflicts only (m136)
  __shared__ u16 Bs[2][64][72];
  __shared__ float Gs[64][68];

  const int tid = threadIdx.x;
  const int m0 = (second ? (blockIdx.y - 4) : blockIdx.y) * 64;
  const int n0 = blockIdx.x * 64;
  const int ub = n0 >> 2;        // first hidden unit of this block
  const int r = tid >> 2;        // staging row 0..63
  const int q = tid & 3;         // staging 16-col group
  const int lane = tid & 63;
  const int wv = tid >> 6;
  const int wm = (wv >> 1) * 32;
  const int wn = (wv & 1) * 32;
  const int l16 = lane & 15;
  const int quad = lane >> 4;

  const int klen0 = d.klen0;
  const u16* aw0 = d.A0 + (size_t)(m0 + r) * d.lda0;
  const u16* aw1 = d.A1 + (size_t)(m0 + r) * d.lda1;
  const int orow = (r & 3) * H_ + ub + (r >> 2);  // gate-col n0+r -> original W row
  const u16* bw0_h = (const u16*)d.W0 + (size_t)orow * d.ldw0;
  const u16* bw1_h = (const u16*)d.W1 + (size_t)orow * d.ldw1;
  const float* bw0_f = (const float*)d.W0 + (size_t)orow * d.ldw0;
  const float* bw1_f = (const float*)d.W1 + (size_t)orow * d.ldw1;

  // two register slots (chunk parity): p = even chunks, q = odd chunks
  uint4 pa0, pa1, pb0, pb1;
  uint4 qa0, qa1, qb0, qb1;
  float4 pf0, pf1, pf2, pf3, qf0, qf1, qf2, qf3;

  auto load_to = [&](int kc, uint4& A0r, uint4& A1r, uint4& B0r, uint4& B1r,
                     float4& F0, float4& F1, float4& F2, float4& F3) {
    const int kg = kc * 64 + q * 16;
    const bool first = kg < klen0;
    const u16* pa = first ? (aw0 + kg) : (aw1 + (kg - klen0));
    A0r = *(const uint4*)pa;
    A1r = *(const uint4*)(pa + 8);
    if constexpr (WF32) {
      const float* pb = first ? (bw0_f + kg) : (bw1_f + (kg - klen0));
      F0 = *(const float4*)pb;
      F1 = *(const float4*)(pb + 4);
      F2 = *(const float4*)(pb + 8);
      F3 = *(const float4*)(pb + 12);
    } else {
      const u16* pb = first ? (bw0_h + kg) : (bw1_h + (kg - klen0));
      B0r = *(const uint4*)pb;
      B1r = *(const uint4*)(pb + 8);
    }
  };

  auto write_to = [&](int buf, uint4& A0r, uint4& A1r, uint4& B0r, uint4& B1r,
                      float4& F0, float4& F1, float4& F2, float4& F3) {
    uint4 w0 = B0r, w1 = B1r;
    if constexpr (WF32) {
      w0 = make_uint4(pack2(F0.x, F0.y), pack2(F0.z, F0.w),
                      pack2(F1.x, F1.y), pack2(F1.z, F1.w));
      w1 = make_uint4(pack2(F2.x, F2.y), pack2(F2.z, F2.w),
                      pack2(F3.x, F3.y), pack2(F3.z, F3.w));
    }
    *(uint4*)&As[buf][r][q * 16]     = A0r;
    *(uint4*)&As[buf][r][q * 16 + 8] = A1r;
    *(uint4*)&Bs[buf][r][q * 16]     = w0;
    *(uint4*)&Bs[buf][r][q * 16 + 8] = w1;
  };

  float4v acc00 = {}, acc01 = {}, acc10 = {}, acc11 = {};
  auto mfma_step = [&](int buf) {
#pragma unroll
    for (int ks = 0; ks < 2; ++ks) {
      const int kb = ks * 32 + quad * 8;
      short8 a0 = *(const short8*)&As[buf][wm + l16][kb];
      short8 a1 = *(const short8*)&As[buf][wm + 16 + l16][kb];
      short8 b0 = *(const short8*)&Bs[buf][wn + l16][kb];
      short8 b1 = *(const short8*)&Bs[buf][wn + 16 + l16][kb];
      acc00 = __builtin_amdgcn_mfma_f32_16x16x32_bf16(a0, b0, acc00, 0, 0, 0);
      acc01 = __builtin_amdgcn_mfma_f32_16x16x32_bf16(a0, b1, acc01, 0, 0, 0);
      acc10 = __builtin_amdgcn_mfma_f32_16x16x32_bf16(a1, b0, acc10, 0, 0, 0);
      acc11 = __builtin_amdgcn_mfma_f32_16x16x32_bf16(a1, b1, acc11, 0, 0, 0);
    }
  };

  const int nch = d.Ktot >> 6;
  load_to(0, pa0, pa1, pb0, pb1, pf0, pf1, pf2, pf3);
  if (nch > 1) load_to(1, qa0, qa1, qb0, qb1, qf0, qf1, qf2, qf3);
  write_to(0, pa0, pa1, pb0, pb1, pf0, pf1, pf2, pf3);
  __syncthreads();
  for (int kc = 0; kc < nch; ++kc) {
    if ((kc & 1) == 0) {
      // chunk kc+1 (odd) sits in slot q; slot p (chunk kc) is free after its write
      if (kc + 1 < nch) write_to(1, qa0, qa1, qb0, qb1, qf0, qf1, qf2, qf3);
      if (kc + 2 < nch) load_to(kc + 2, pa0, pa1, pb0, pb1, pf0, pf1, pf2, pf3);
      mfma_step(0);
    } else {
      if (kc + 1 < nch) write_to(0, pa0, pa1, pb0, pb1, pf0, pf1, pf2, pf3);
      if (kc + 2 < nch) load_to(kc + 2, qa0, qa1, qb0, qb1, qf0, qf1, qf2, qf3);
      mfma_step(1);
    }
    __syncthreads();  // writes to buf[(kc+1)&1] visible; reads of buf[kc&1] done
  }

  // spill gates to LDS (C/D layout: col = lane&15, row = quad*4 + reg)
#pragma unroll
  for (int rr = 0; rr < 4; ++rr) {
    Gs[wm + quad * 4 + rr][wn + l16]           = acc00[rr];
    Gs[wm + quad * 4 + rr][wn + 16 + l16]      = acc01[rr];
    Gs[wm + 16 + quad * 4 + rr][wn + l16]      = acc10[rr];
    Gs[wm + 16 + quad * 4 + rr][wn + 16 + l16] = acc11[rr];
  }
  __syncthreads();

  // fused LSTM cell: 64 batches x 16 units; local col 4u+g = gate g of unit ub+u
#pragma unroll
  for (int it = 0; it < 4; ++it) {
    const int p = tid + it * 256;
    const int bl = p >> 4;
    const int u = p & 15;
    const int J = ub + u;
    const int bg = m0 + bl;
    const float4v g = *(const float4v*)&Gs[bl][u * 4];
    float pi = g[0] + d.bias[J];
    float pf = g[1] + d.bias[H_ + J];
    float pg = g[2] + d.bias[2 * H_ + J];
    float po = g[3] + d.bias[3 * H_ + J];
    if (d.inp != nullptr) {
      const float iv = d.inp[bg];
      pi += iv * d.wcol[J];
      pf += iv * d.wcol[H_ + J];
      pg += iv * d.wcol[2 * H_ + J];
      po += iv * d.wcol[3 * H_ + J];
    }
    const size_t idx = (size_t)bg * H_ + J;
    const float c = d.c[idx];
    const float cn = sigm(pf) * c + sigm(pi) * tanh_(pg);
    d.c[idx] = cn;
    d.h[idx] = f2bf(sigm(po) * tanh_(cn));
  }
}

// pred[b] = fc_W . h1[b] + fc_b ; fp32 out + fp32 feedback
__global__ __launch_bounds__(256) void fc_kernel(
    const u16* __restrict__ h1, const float* __restrict__ fcW,
    const float* __restrict__ fcb, float* __restrict__ out,
    float* __restrict__ inp, int t)
{
  const int b = blockIdx.x;
  const int tid = threadIdx.x;
  const u16* hr = h1 + (size_t)b * H_ + tid * 4;
  const float* wr = fcW + tid * 4;
  float s = 0.f;
#pragma unroll
  for (int j = 0; j < 4; ++j) s += bf2f(hr[j]) * wr[j];
#pragma unroll
  for (int off = 32; off > 0; off >>= 1) s += __shfl_down(s, off, 64);
  __shared__ float red[4];
  if ((tid & 63) == 0) red[tid >> 6] = s;
  __syncthreads();
  if (tid == 0) {
    const float p = red[0] + red[1] + red[2] + red[3] + fcb[0];
    out[(size_t)b * TOUT + t] = p;
    inp[b] = p;
  }
}

extern "C" void kernel_launch(void* const* d_in, const int* in_sizes, int n_in,
                              void* d_out, int out_size, void* d_ws, size_t ws_size,
                              hipStream_t stream)
{
  const float* X     = (const float*)d_in[0];
  const float* eWih0 = (const float*)d_in[1];
  const float* eWhh0 = (const float*)d_in[2];
  const float* eb0   = (const float*)d_in[3];
  const float* eWih1 = (const float*)d_in[4];
  const float* eWhh1 = (const float*)d_in[5];
  const float* eb1   = (const float*)d_in[6];
  const float* dWih0 = (const float*)d_in[7];
  const float* dWhh0 = (const float*)d_in[8];
  const float* db0   = (const float*)d_in[9];
  const float* dWih1 = (const float*)d_in[10];
  const float* dWhh1 = (const float*)d_in[11];
  const float* db1   = (const float*)d_in[12];
  const float* fcW   = (const float*)d_in[13];
  const float* fcb   = (const float*)d_in[14];
  float* out = (float*)d_out;

  char* ws = (char*)d_ws;
  size_t off = 0;
  auto alloc = [&](size_t bytes) -> void* {
    void* p = ws + off;
    off += (bytes + 255) & ~(size_t)255;
    return p;
  };
  // state block first (zeroed every call)
  u16* h0buf[2], *h1buf[2];
  h0buf[0] = (u16*)alloc((size_t)B_ * H_ * 2);
  h0buf[1] = (u16*)alloc((size_t)B_ * H_ * 2);
  h1buf[0] = (u16*)alloc((size_t)B_ * H_ * 2);
  h1buf[1] = (u16*)alloc((size_t)B_ * H_ * 2);
  float* C0  = (float*)alloc((size_t)B_ * H_ * 4);
  float* C1  = (float*)alloc((size_t)B_ * H_ * 4);
  float* INP = (float*)alloc(B_ * 4);
  const size_t zbytes = off;
  u16* XB = (u16*)alloc((size_t)B_ * S_ * D_ * 2);
  // bf16 weight copies (fast path), original flat layouts
  u16* WB_eWih0 = (u16*)alloc((size_t)G4 * D_ * 2);
  u16* WB_eWhh0 = (u16*)alloc((size_t)G4 * H_ * 2);
  u16* WB_eWih1 = (u16*)alloc((size_t)G4 * H_ * 2);
  u16* WB_eWhh1 = (u16*)alloc((size_t)G4 * H_ * 2);
  u16* WB_dWhh0 = (u16*)alloc((size_t)G4 * H_ * 2);
  u16* WB_dWih1 = (u16*)alloc((size_t)G4 * H_ * 2);
  u16* WB_dWhh1 = (u16*)alloc((size_t)G4 * H_ * 2);
  const size_t need_full = off;
  const bool fast = (ws_size >= need_full);

  zero_kernel<<<dim3(256), dim3(256), 0, stream>>>((uint4*)ws, (int)(zbytes / 16));
  cvt_kernel<<<dim3(1024), dim3(256), 0, stream>>>(X, XB, B_ * S_ * D_);
  if (fast) {
    cvt_kernel<<<dim3(256), dim3(256), 0, stream>>>(eWih0, WB_eWih0, G4 * D_);
    cvt_kernel<<<dim3(1024), dim3(256), 0, stream>>>(eWhh0, WB_eWhh0, G4 * H_);
    cvt_kernel<<<dim3(1024), dim3(256), 0, stream>>>(eWih1, WB_eWih1, G4 * H_);
    cvt_kernel<<<dim3(1024), dim3(256), 0, stream>>>(eWhh1, WB_eWhh1, G4 * H_);
    cvt_kernel<<<dim3(1024), dim3(256), 0, stream>>>(dWhh0, WB_dWhh0, G4 * H_);
    cvt_kernel<<<dim3(1024), dim3(256), 0, stream>>>(dWih1, WB_dWih1, G4 * H_);
    cvt_kernel<<<dim3(1024), dim3(256), 0, stream>>>(dWhh1, WB_dWhh1, G4 * H_);
  }

  auto mk = [&](const u16* A0, int lda0, const u16* A1, int lda1, int klen0,
                const void* W0b, const void* W0f, int ldw0,
                const void* W1b, const void* W1f, int ldw1, int Ktot,
                const float* bias, const float* wcol, const float* inp,
                float* c, u16* h) {
    LayerDesc d;
    d.A0 = A0; d.lda0 = lda0; d.A1 = A1; d.lda1 = lda1; d.klen0 = klen0;
    d.W0 = fast ? W0b : W0f; d.ldw0 = ldw0;
    d.W1 = fast ? W1b : W1f; d.ldw1 = ldw1; d.Ktot = Ktot;
    d.bias = bias; d.wcol = wcol; d.inp = inp; d.c = c; d.h = h;
    d.active = 1;
    return d;
  };
  LayerDesc off_d = {};
  off_d.active = 0;

  auto launch = [&](dim3 grid, const LayerDesc& a, const LayerDesc& b) {
    if (fast)
      lstm_step_kernel<false><<<grid, dim3(256), 0, stream>>>(a, b);
    else
      lstm_step_kernel<true><<<grid, dim3(256), 0, stream>>>(a, b);
  };

  // encoder, layer-pipelined: tick u runs L0(t=u) and L1(t=u-1) concurrently.
  // h ping-pong: L(t) reads hbuf[t&1], writes hbuf[(t+1)&1].
  for (int u = 0; u <= S_; ++u) {
    LayerDesc d0 = off_d, d1 = off_d;
    if (u < S_) {
      const int t = u;
      d0 = mk(XB + t * D_, S_ * D_, h0buf[t & 1], H_, D_,
              WB_eWih0, eWih0, D_, WB_eWhh0, eWhh0, H_, 1088,
              eb0, nullptr, nullptr, C0, h0buf[(t + 1) & 1]);
    }
    if (u >= 1) {
      const int t = u - 1;
      d1 = mk(h0buf[(t + 1) & 1], H_, h1buf[t & 1], H_, H_,
              WB_eWih1, eWih1, H_, WB_eWhh1, eWhh1, H_, 2048,
              eb1, nullptr, nullptr, C1, h1buf[(t + 1) & 1]);
    }
    launch(dim3(64, 8), d0, d1);
  }

  // decoder: strictly sequential (pred feedback), single-layer launches
  for (int t = 0; t < TOUT; ++t) {
    u16* h0i = h0buf[t & 1]; u16* h0o = h0buf[(t + 1) & 1];
    u16* h1i = h1buf[t & 1]; u16* h1o = h1buf[(t + 1) & 1];
    LayerDesc dl0 = mk(h0i, H_, h0i, H_, 1024,
                       WB_dWhh0, dWhh0, H_, WB_dWhh0, dWhh0, H_, 1024,
                       db0, dWih0, INP, C0, h0o);
    launch(dim3(64, 4), dl0, off_d);
    LayerDesc dl1 = mk(h0o, H_, h1i, H_, H_,
                       WB_dWih1, dWih1, H_, WB_dWhh1, dWhh1, H_, 2048,
                       db1, nullptr, nullptr, C1, h1o);
    launch(dim3(64, 4), dl1, off_d);
    fc_kernel<<<dim3(B_), dim3(256), 0, stream>>>(h1o, fcW, fcb, out, INP, t);
  }
}

// Round 5
// 8600.114 us; speedup vs baseline: 1.0296x; 1.0296x over previous
//
#include <hip/hip_runtime.h>

#define B_ 256
#define S_ 256
#define D_ 64
#define H_ 1024
#define G4 4096
#define TOUT 32

typedef unsigned short u16;
typedef __attribute__((ext_vector_type(8))) short short8;
typedef __attribute__((ext_vector_type(4))) float float4v;

__device__ __forceinline__ float bf2f(u16 b) {
  return __uint_as_float(((unsigned int)b) << 16);
}
__device__ __forceinline__ u16 f2bf(float f) {
  unsigned int u = __float_as_uint(f);
  unsigned int r = (u + 0x7fffu + ((u >> 16) & 1u)) >> 16;
  return (u16)r;
}
__device__ __forceinline__ unsigned pack2(float a, float b) {
  return (unsigned)f2bf(a) | ((unsigned)f2bf(b) << 16);
}
__device__ __forceinline__ float sigm(float x) {
  return 1.f / (1.f + __expf(-x));
}
__device__ __forceinline__ float tanh_(float x) {
  float xc = fminf(fmaxf(x, -15.f), 15.f);
  float e = __expf(2.f * xc);
  return (e - 1.f) / (e + 1.f);
}

__global__ __launch_bounds__(256) void cvt_kernel(const float* __restrict__ src,
                                                  u16* __restrict__ dst, int n) {
  for (int i = blockIdx.x * blockDim.x + threadIdx.x; i < n;
       i += gridDim.x * blockDim.x)
    dst[i] = f2bf(src[i]);
}

__global__ __launch_bounds__(256) void zero_kernel(uint4* __restrict__ p, int n16) {
  for (int i = blockIdx.x * blockDim.x + threadIdx.x; i < n16;
       i += gridDim.x * blockDim.x)
    p[i] = make_uint4(0u, 0u, 0u, 0u);
}

struct LayerDesc {
  const u16* A0; int lda0;
  const u16* A1; int lda1; int klen0;
  const void* W0; int ldw0;
  const void* W1; int ldw1; int Ktot;
  const float* bias;   // fp32 [4096] original gate-blocked
  const float* wcol;   // fp32 [4096] dec input column, or null
  const float* inp;    // fp32 [B] scalar input, or null
  float* c;
  u16* h;
  int active;
};

// Paired LSTM step: blockIdx.y<4 -> dA (layer0 @ t), >=4 -> dB (layer1 @ t-1).
// gates = [A0|A1] @ [W0|W1]^T + bias (+inp*wcol), fused cell epilogue.
//
// NO LDS / NO BARRIERS in the K-loop: A and B fragments are loaded straight
// from global into MFMA register layout (lane reads A[m + l16][k + quad*8]
// as one dwordx4). Each wave owns a disjoint interleaved quarter of the
// 32-wide K-chunks and accumulates a full 64x64 fp32 partial (4x4 tiles,
// 64 VGPRs). One-chunk register prefetch; compiler schedules vmcnt finely
// since no s_barrier ever drains the load queue. Cross-wave reduction once
// at the end via 32 KB LDS (waves 0/1 write, 2/3 add), then fused cell.
template <bool WF32>
__global__ __launch_bounds__(256, 2) void lstm_step_kernel(LayerDesc dA, LayerDesc dB)
{
  const bool second = (blockIdx.y >= 4);
  const LayerDesc d = second ? dB : dA;
  if (!d.active) return;

  __shared__ float Gs[2][64][64];

  const int tid = threadIdx.x;
  const int m0 = (second ? (blockIdx.y - 4) : blockIdx.y) * 64;
  const int n0 = blockIdx.x * 64;
  const int ub = n0 >> 2;        // first hidden unit of this block
  const int lane = tid & 63;
  const int wv = tid >> 6;
  const int l16 = lane & 15;
  const int quad = lane >> 4;

  // per-fragment global base pointers; quad covers k-offset quad*8
  const u16* aP0[4]; const u16* aP1[4];
  const void* bP0[4]; const void* bP1[4];
#pragma unroll
  for (int i = 0; i < 4; ++i) {
    const int am = m0 + i * 16 + l16;
    aP0[i] = d.A0 + (size_t)am * d.lda0 + quad * 8;
    aP1[i] = d.A1 + (size_t)am * d.lda1 + quad * 8;
  }
#pragma unroll
  for (int j = 0; j < 4; ++j) {
    const int p = n0 + j * 16 + l16;               // gate-col (interleaved order)
    const int orow = (p & 3) * H_ + (p >> 2);      // -> original torch W row
    if constexpr (WF32) {
      bP0[j] = (const void*)((const float*)d.W0 + (size_t)orow * d.ldw0 + quad * 8);
      bP1[j] = (const void*)((const float*)d.W1 + (size_t)orow * d.ldw1 + quad * 8);
    } else {
      bP0[j] = (const void*)((const u16*)d.W0 + (size_t)orow * d.ldw0 + quad * 8);
      bP1[j] = (const void*)((const u16*)d.W1 + (size_t)orow * d.ldw1 + quad * 8);
    }
  }

  const int klen0 = d.klen0;
  auto ldfr = [&](int c, short8* fa, short8* fb) {
    const int k0 = c * 32;
    const bool f = k0 < klen0;
    const int ka = f ? k0 : (k0 - klen0);
#pragma unroll
    for (int i = 0; i < 4; ++i)
      fa[i] = *(const short8*)((f ? aP0[i] : aP1[i]) + ka);
#pragma unroll
    for (int j = 0; j < 4; ++j) {
      if constexpr (WF32) {
        const float* pb = (const float*)(f ? bP0[j] : bP1[j]) + ka;
        const float4 x0 = *(const float4*)pb;
        const float4 x1 = *(const float4*)(pb + 4);
        union { uint4 u; short8 s; } cv;
        cv.u = make_uint4(pack2(x0.x, x0.y), pack2(x0.z, x0.w),
                          pack2(x1.x, x1.y), pack2(x1.z, x1.w));
        fb[j] = cv.s;
      } else {
        fb[j] = *(const short8*)((const u16*)(f ? bP0[j] : bP1[j]) + ka);
      }
    }
  };

  float4v acc[4][4];
#pragma unroll
  for (int i = 0; i < 4; ++i)
#pragma unroll
    for (int j = 0; j < 4; ++j) acc[i][j] = (float4v){0.f, 0.f, 0.f, 0.f};

  auto domfma = [&](short8* fa, short8* fb) {
#pragma unroll
    for (int i = 0; i < 4; ++i)
#pragma unroll
      for (int j = 0; j < 4; ++j)
        acc[i][j] = __builtin_amdgcn_mfma_f32_16x16x32_bf16(fa[i], fb[j],
                                                            acc[i][j], 0, 0, 0);
  };

  // interleaved K-quarters: wave wv takes chunks wv, wv+4, wv+8, ...
  const int nch = d.Ktot >> 5;  // 32-wide chunks
  int c = wv;
  short8 sa0[4], sb0[4], sa1[4], sb1[4];
  if (c < nch) ldfr(c, sa0, sb0);
  while (c < nch) {
    if (c + 4 < nch) ldfr(c + 4, sa1, sb1);   // in flight across MFMA below
    domfma(sa0, sb0);
    c += 4;
    if (c >= nch) break;
    if (c + 4 < nch) ldfr(c + 4, sa0, sb0);
    domfma(sa1, sb1);
    c += 4;
  }

  // cross-wave reduction: waves 0/1 write their partials, waves 2/3 add
  // (C/D layout: col = lane&15, row = quad*4 + reg)
  if (wv < 2) {
#pragma unroll
    for (int i = 0; i < 4; ++i)
#pragma unroll
      for (int j = 0; j < 4; ++j)
#pragma unroll
        for (int rr = 0; rr < 4; ++rr)
          Gs[wv][i * 16 + quad * 4 + rr][j * 16 + l16] = acc[i][j][rr];
  }
  __syncthreads();
  if (wv >= 2) {
#pragma unroll
    for (int i = 0; i < 4; ++i)
#pragma unroll
      for (int j = 0; j < 4; ++j)
#pragma unroll
        for (int rr = 0; rr < 4; ++rr)
          Gs[wv - 2][i * 16 + quad * 4 + rr][j * 16 + l16] += acc[i][j][rr];
  }
  __syncthreads();

  // fused LSTM cell: 64 batches x 16 units; local col 4u+g = gate g of unit ub+u
#pragma unroll
  for (int it = 0; it < 4; ++it) {
    const int p = tid + it * 256;
    const int bl = p >> 4;
    const int u = p & 15;
    const int J = ub + u;
    const int bg = m0 + bl;
    const float4v g = *(const float4v*)&Gs[0][bl][u * 4] +
                      *(const float4v*)&Gs[1][bl][u * 4];
    float pi = g[0] + d.bias[J];
    float pf = g[1] + d.bias[H_ + J];
    float pg = g[2] + d.bias[2 * H_ + J];
    float po = g[3] + d.bias[3 * H_ + J];
    if (d.inp != nullptr) {
      const float iv = d.inp[bg];
      pi += iv * d.wcol[J];
      pf += iv * d.wcol[H_ + J];
      pg += iv * d.wcol[2 * H_ + J];
      po += iv * d.wcol[3 * H_ + J];
    }
    const size_t idx = (size_t)bg * H_ + J;
    const float cc = d.c[idx];
    const float cn = sigm(pf) * cc + sigm(pi) * tanh_(pg);
    d.c[idx] = cn;
    d.h[idx] = f2bf(sigm(po) * tanh_(cn));
  }
}

// pred[b] = fc_W . h1[b] + fc_b ; fp32 out + fp32 feedback
__global__ __launch_bounds__(256) void fc_kernel(
    const u16* __restrict__ h1, const float* __restrict__ fcW,
    const float* __restrict__ fcb, float* __restrict__ out,
    float* __restrict__ inp, int t)
{
  const int b = blockIdx.x;
  const int tid = threadIdx.x;
  const u16* hr = h1 + (size_t)b * H_ + tid * 4;
  const float* wr = fcW + tid * 4;
  float s = 0.f;
#pragma unroll
  for (int j = 0; j < 4; ++j) s += bf2f(hr[j]) * wr[j];
#pragma unroll
  for (int off = 32; off > 0; off >>= 1) s += __shfl_down(s, off, 64);
  __shared__ float red[4];
  if ((tid & 63) == 0) red[tid >> 6] = s;
  __syncthreads();
  if (tid == 0) {
    const float p = red[0] + red[1] + red[2] + red[3] + fcb[0];
    out[(size_t)b * TOUT + t] = p;
    inp[b] = p;
  }
}

extern "C" void kernel_launch(void* const* d_in, const int* in_sizes, int n_in,
                              void* d_out, int out_size, void* d_ws, size_t ws_size,
                              hipStream_t stream)
{
  const float* X     = (const float*)d_in[0];
  const float* eWih0 = (const float*)d_in[1];
  const float* eWhh0 = (const float*)d_in[2];
  const float* eb0   = (const float*)d_in[3];
  const float* eWih1 = (const float*)d_in[4];
  const float* eWhh1 = (const float*)d_in[5];
  const float* eb1   = (const float*)d_in[6];
  const float* dWih0 = (const float*)d_in[7];
  const float* dWhh0 = (const float*)d_in[8];
  const float* db0   = (const float*)d_in[9];
  const float* dWih1 = (const float*)d_in[10];
  const float* dWhh1 = (const float*)d_in[11];
  const float* db1   = (const float*)d_in[12];
  const float* fcW   = (const float*)d_in[13];
  const float* fcb   = (const float*)d_in[14];
  float* out = (float*)d_out;

  char* ws = (char*)d_ws;
  size_t off = 0;
  auto alloc = [&](size_t bytes) -> void* {
    void* p = ws + off;
    off += (bytes + 255) & ~(size_t)255;
    return p;
  };
  // state block first (zeroed every call)
  u16* h0buf[2], *h1buf[2];
  h0buf[0] = (u16*)alloc((size_t)B_ * H_ * 2);
  h0buf[1] = (u16*)alloc((size_t)B_ * H_ * 2);
  h1buf[0] = (u16*)alloc((size_t)B_ * H_ * 2);
  h1buf[1] = (u16*)alloc((size_t)B_ * H_ * 2);
  float* C0  = (float*)alloc((size_t)B_ * H_ * 4);
  float* C1  = (float*)alloc((size_t)B_ * H_ * 4);
  float* INP = (float*)alloc(B_ * 4);
  const size_t zbytes = off;
  u16* XB = (u16*)alloc((size_t)B_ * S_ * D_ * 2);
  // bf16 weight copies (fast path), original flat layouts
  u16* WB_eWih0 = (u16*)alloc((size_t)G4 * D_ * 2);
  u16* WB_eWhh0 = (u16*)alloc((size_t)G4 * H_ * 2);
  u16* WB_eWih1 = (u16*)alloc((size_t)G4 * H_ * 2);
  u16* WB_eWhh1 = (u16*)alloc((size_t)G4 * H_ * 2);
  u16* WB_dWhh0 = (u16*)alloc((size_t)G4 * H_ * 2);
  u16* WB_dWih1 = (u16*)alloc((size_t)G4 * H_ * 2);
  u16* WB_dWhh1 = (u16*)alloc((size_t)G4 * H_ * 2);
  const size_t need_full = off;
  const bool fast = (ws_size >= need_full);

  zero_kernel<<<dim3(256), dim3(256), 0, stream>>>((uint4*)ws, (int)(zbytes / 16));
  cvt_kernel<<<dim3(1024), dim3(256), 0, stream>>>(X, XB, B_ * S_ * D_);
  if (fast) {
    cvt_kernel<<<dim3(256), dim3(256), 0, stream>>>(eWih0, WB_eWih0, G4 * D_);
    cvt_kernel<<<dim3(1024), dim3(256), 0, stream>>>(eWhh0, WB_eWhh0, G4 * H_);
    cvt_kernel<<<dim3(1024), dim3(256), 0, stream>>>(eWih1, WB_eWih1, G4 * H_);
    cvt_kernel<<<dim3(1024), dim3(256), 0, stream>>>(eWhh1, WB_eWhh1, G4 * H_);
    cvt_kernel<<<dim3(1024), dim3(256), 0, stream>>>(dWhh0, WB_dWhh0, G4 * H_);
    cvt_kernel<<<dim3(1024), dim3(256), 0, stream>>>(dWih1, WB_dWih1, G4 * H_);
    cvt_kernel<<<dim3(1024), dim3(256), 0, stream>>>(dWhh1, WB_dWhh1, G4 * H_);
  }

  auto mk = [&](const u16* A0, int lda0, const u16* A1, int lda1, int klen0,
                const void* W0b, const void* W0f, int ldw0,
                const void* W1b, const void* W1f, int ldw1, int Ktot,
                const float* bias, const float* wcol, const float* inp,
                float* c, u16* h) {
    LayerDesc d;
    d.A0 = A0; d.lda0 = lda0; d.A1 = A1; d.lda1 = lda1; d.klen0 = klen0;
    d.W0 = fast ? W0b : W0f; d.ldw0 = ldw0;
    d.W1 = fast ? W1b : W1f; d.ldw1 = ldw1; d.Ktot = Ktot;
    d.bias = bias; d.wcol = wcol; d.inp = inp; d.c = c; d.h = h;
    d.active = 1;
    return d;
  };
  LayerDesc off_d = {};
  off_d.active = 0;

  auto launch = [&](dim3 grid, const LayerDesc& a, const LayerDesc& b) {
    if (fast)
      lstm_step_kernel<false><<<grid, dim3(256), 0, stream>>>(a, b);
    else
      lstm_step_kernel<true><<<grid, dim3(256), 0, stream>>>(a, b);
  };

  // encoder, layer-pipelined: tick u runs L0(t=u) and L1(t=u-1) concurrently.
  // h ping-pong: L(t) reads hbuf[t&1], writes hbuf[(t+1)&1].
  for (int u = 0; u <= S_; ++u) {
    LayerDesc d0 = off_d, d1 = off_d;
    if (u < S_) {
      const int t = u;
      d0 = mk(XB + t * D_, S_ * D_, h0buf[t & 1], H_, D_,
              WB_eWih0, eWih0, D_, WB_eWhh0, eWhh0, H_, 1088,
              eb0, nullptr, nullptr, C0, h0buf[(t + 1) & 1]);
    }
    if (u >= 1) {
      const int t = u - 1;
      d1 = mk(h0buf[(t + 1) & 1], H_, h1buf[t & 1], H_, H_,
              WB_eWih1, eWih1, H_, WB_eWhh1, eWhh1, H_, 2048,
              eb1, nullptr, nullptr, C1, h1buf[(t + 1) & 1]);
    }
    launch(dim3(64, 8), d0, d1);
  }

  // decoder: strictly sequential (pred feedback), single-layer launches
  for (int t = 0; t < TOUT; ++t) {
    u16* h0i = h0buf[t & 1]; u16* h0o = h0buf[(t + 1) & 1];
    u16* h1i = h1buf[t & 1]; u16* h1o = h1buf[(t + 1) & 1];
    LayerDesc dl0 = mk(h0i, H_, h0i, H_, 1024,
                       WB_dWhh0, dWhh0, H_, WB_dWhh0, dWhh0, H_, 1024,
                       db0, dWih0, INP, C0, h0o);
    launch(dim3(64, 4), dl0, off_d);
    LayerDesc dl1 = mk(h0o, H_, h1i, H_, H_,
                       WB_dWih1, dWih1, H_, WB_dWhh1, dWhh1, H_, 2048,
                       db1, nullptr, nullptr, C1, h1o);
    launch(dim3(64, 4), dl1, off_d);
    fc_kernel<<<dim3(B_), dim3(256), 0, stream>>>(h1o, fcW, fcb, out, INP, t);
  }
}